// Round 5
// baseline (94.220 us; speedup 1.0000x reference)
//
#include <hip/hip_runtime.h>
#include <math.h>

// RotatedIoULoss: per-pair rotated-box IoU loss, mean-reduced to one f32 scalar.
// Inputs: d_in[0]=pred (n,5) f32, d_in[1]=target (n,5) f32, d_in[2]=weight (n,) f32.
// Output: d_out[0] = mean(-log(max(iou,1e-6)) * weight).
//
// R1: branchless Green's-theorem intersection (generic halfplane Liang-Barsky).
// R2: 4 boxes/thread, float4 loads.
// R3: rectangle-aware AABB slab clipping (~330 VALU-equiv/box).
// R4: explicit 4-wide SoA interleave — every step is an unrolled k=0..3 loop
//     over the thread's 4 boxes, so the static schedule carries ILP=4 through
//     the entire clip dependency chain (R2/R3 left interleaving to the
//     compiler; VALUBusy ~26% said it didn't).

__device__ __forceinline__ float rcpf(float x) { return __builtin_amdgcn_rcpf(x); }

// Scalar edge clip vs AABB [-hw,hw]x[-hh,hh]; Green cross term + optional
// net-displacement tracking. Called inside unrolled k-loops (SoA interleave).
template <bool TRACK>
__device__ __forceinline__ void clip_edge(float u0, float v0, float dx, float dy,
                                          float rx, float ry, float hw, float hh,
                                          float& S, float& Dx, float& Dy)
{
    float ta = (-hw - u0) * rx;
    float tb = ( hw - u0) * rx;
    float tc = (-hh - v0) * ry;
    float td = ( hh - v0) * ry;
    float tumin = fminf(ta, tb), tumax = fmaxf(ta, tb);
    float tvmin = fminf(tc, td), tvmax = fmaxf(tc, td);
    float t0 = fmaxf(fmaxf(tumin, tvmin), 0.0f);   // v_max3
    float t1 = fminf(fminf(tumax, tvmax), 1.0f);   // v_min3
    bool valid = t1 > t0;
    float sx = fmaf(t0, dx, u0), sy = fmaf(t0, dy, v0);
    float ex = fmaf(t1, dx, u0), ey = fmaf(t1, dy, v0);
    float c = sx * ey - sy * ex;
    S += valid ? c : 0.0f;
    if (TRACK) {
        Dx += valid ? (ex - sx) : 0.0f;
        Dy += valid ? (ey - sy) : 0.0f;
    }
}

// 4-wide SoA quad-vs-AABB clip. Quad k: center (cx,cy), half-axis vectors
// U,V (CCW corners +U+V,-U+V,-U-V,+U-V), clip box (hw,hh).
template <bool TRACK>
__device__ __forceinline__ void clip_quad4(const float* Ux, const float* Uy,
                                           const float* Vx, const float* Vy,
                                           const float* cx, const float* cy,
                                           const float* hw, const float* hh,
                                           float* S, float* Dx, float* Dy)
{
    float d0x[4], d0y[4], d1x[4], d1y[4];
    float r0x[4], r0y[4], r1x[4], r1y[4];
    float c0x[4], c0y[4], c3x[4], c3y[4];
    #pragma unroll
    for (int k = 0; k < 4; k++) {
        d0x[k] = -2.0f * Ux[k]; d0y[k] = -2.0f * Uy[k];   // edge0 (+), edge2 (-)
        d1x[k] = -2.0f * Vx[k]; d1y[k] = -2.0f * Vy[k];   // edge1 (+), edge3 (-)
        r0x[k] = rcpf(d0x[k]);  r0y[k] = rcpf(d0y[k]);
        r1x[k] = rcpf(d1x[k]);  r1y[k] = rcpf(d1y[k]);
        c0x[k] = Ux[k] + Vx[k]; c0y[k] = Uy[k] + Vy[k];   // corner 0 offset
        c3x[k] = Ux[k] - Vx[k]; c3y[k] = Uy[k] - Vy[k];   // corner 3 offset
    }
    #pragma unroll
    for (int k = 0; k < 4; k++)   // edge 0: start c0, dir d0
        clip_edge<TRACK>( c0x[k] + cx[k],  c0y[k] + cy[k],  d0x[k],  d0y[k],
                          r0x[k],  r0y[k], hw[k], hh[k], S[k], Dx[k], Dy[k]);
    #pragma unroll
    for (int k = 0; k < 4; k++)   // edge 1: start c1=-c3off, dir d1
        clip_edge<TRACK>(-c3x[k] + cx[k], -c3y[k] + cy[k],  d1x[k],  d1y[k],
                          r1x[k],  r1y[k], hw[k], hh[k], S[k], Dx[k], Dy[k]);
    #pragma unroll
    for (int k = 0; k < 4; k++)   // edge 2: start c2=-c0off, dir -d0
        clip_edge<TRACK>(-c0x[k] + cx[k], -c0y[k] + cy[k], -d0x[k], -d0y[k],
                         -r0x[k], -r0y[k], hw[k], hh[k], S[k], Dx[k], Dy[k]);
    #pragma unroll
    for (int k = 0; k < 4; k++)   // edge 3: start c3, dir -d1
        clip_edge<TRACK>( c3x[k] + cx[k],  c3y[k] + cy[k], -d1x[k], -d1y[k],
                         -r1x[k], -r1y[k], hw[k], hh[k], S[k], Dx[k], Dy[k]);
}

__global__ void __launch_bounds__(256)
riou_loss_kernel(const float* __restrict__ pred,
                 const float* __restrict__ target,
                 const float* __restrict__ weight,
                 float* __restrict__ out,
                 int n, float inv_n)
{
    int t = blockIdx.x * blockDim.x + threadIdx.x;
    int base = t * 4;
    float loss = 0.0f;

    if (base < n) {
        float pp[20], qq[20], ww[4];
        if (base + 4 <= n) {
            // 80 B per thread, 16B-aligned: five float4 loads per input
            const float4* P4 = (const float4*)(pred   + (size_t)base * 5);
            const float4* Q4 = (const float4*)(target + (size_t)base * 5);
            #pragma unroll
            for (int i = 0; i < 5; i++) {
                float4 p = P4[i];
                pp[4 * i + 0] = p.x; pp[4 * i + 1] = p.y;
                pp[4 * i + 2] = p.z; pp[4 * i + 3] = p.w;
                float4 q = Q4[i];
                qq[4 * i + 0] = q.x; qq[4 * i + 1] = q.y;
                qq[4 * i + 2] = q.z; qq[4 * i + 3] = q.w;
            }
            float4 w4 = ((const float4*)weight)[t];
            ww[0] = w4.x; ww[1] = w4.y; ww[2] = w4.z; ww[3] = w4.w;
        } else {
            #pragma unroll
            for (int k = 0; k < 4; k++) {
                int b = base + k; b = (b < n) ? b : (n - 1);
                #pragma unroll
                for (int j = 0; j < 5; j++) {
                    pp[5 * k + j] = pred[(size_t)b * 5 + j];
                    qq[5 * k + j] = target[(size_t)b * 5 + j];
                }
                ww[k] = (base + k < n) ? weight[b] : 0.0f;
            }
        }

        // ---- SoA setup (all unrolled; indices compile-time) ----
        float hw1[4], hh1[4], hw2[4], hh2[4], a12[4];
        float ca[4], sa[4], cr[4], sr[4];
        float cPx[4], cPy[4], cQx[4], cQy[4];
        #pragma unroll
        for (int k = 0; k < 4; k++) {
            float pw = pp[5 * k + 2], ph = pp[5 * k + 3], pa = pp[5 * k + 4];
            float qw = qq[5 * k + 2], qh = qq[5 * k + 3], qa = qq[5 * k + 4];
            hw1[k] = 0.5f * pw; hh1[k] = 0.5f * ph;
            hw2[k] = 0.5f * qw; hh2[k] = 0.5f * qh;
            a12[k] = pw * ph + qw * qh;
            ca[k] = __cosf(pa); sa[k] = __sinf(pa);
            float delta = pa - qa;
            cr[k] = __cosf(delta); sr[k] = __sinf(delta);
        }
        #pragma unroll
        for (int k = 0; k < 4; k++) {
            float ox = qq[5 * k + 0] - pp[5 * k + 0];
            float oy = qq[5 * k + 1] - pp[5 * k + 1];
            // Q center in P-frame: R(-pa) * o
            cPx[k] =  ca[k] * ox + sa[k] * oy;
            cPy[k] = -sa[k] * ox + ca[k] * oy;
            // P center in Q-frame: -R_PQ * cP
            cQx[k] = -(cr[k] * cPx[k] - sr[k] * cPy[k]);
            cQy[k] = -(sr[k] * cPx[k] + cr[k] * cPy[k]);
        }

        float S[4]  = {0, 0, 0, 0};
        float Dx[4] = {0, 0, 0, 0};
        float Dy[4] = {0, 0, 0, 0};

        // Set A: P's quad in Q-frame, clipped to (hw2,hh2). U=R_PQ*(hw1,0),
        // V=R_PQ*(0,hh1).
        {
            float Ux[4], Uy[4], Vx[4], Vy[4];
            #pragma unroll
            for (int k = 0; k < 4; k++) {
                Ux[k] =  cr[k] * hw1[k]; Uy[k] = sr[k] * hw1[k];
                Vx[k] = -sr[k] * hh1[k]; Vy[k] = cr[k] * hh1[k];
            }
            clip_quad4<false>(Ux, Uy, Vx, Vy, cQx, cQy, hw2, hh2, S, Dx, Dy);
        }
        // Set B: Q's quad in P-frame, clipped to (hw1,hh1); track displacement
        // for the frame-translation correction.
        {
            float Ux[4], Uy[4], Vx[4], Vy[4];
            #pragma unroll
            for (int k = 0; k < 4; k++) {
                Ux[k] = cr[k] * hw2[k]; Uy[k] = -sr[k] * hw2[k];
                Vx[k] = sr[k] * hh2[k]; Vy[k] =  cr[k] * hh2[k];
            }
            clip_quad4<true>(Ux, Uy, Vx, Vy, cPx, cPy, hw1, hh1, S, Dx, Dy);
        }

        // 2A = S + cross(cQ, R_PQ * D); loss accumulation
        #pragma unroll
        for (int k = 0; k < 4; k++) {
            float RDx = cr[k] * Dx[k] - sr[k] * Dy[k];
            float RDy = sr[k] * Dx[k] + cr[k] * Dy[k];
            float corr = cQx[k] * RDy - cQy[k] * RDx;
            float inter = fmaxf(0.5f * (S[k] + corr), 0.0f);
            float iou = inter * rcpf(a12[k] - inter);
            iou = fmaxf(iou, 1e-6f);
            loss += -__logf(iou) * ww[k];
        }
    }

    // block reduction: wave shuffle (width 64) -> LDS -> one atomic per block
    #pragma unroll
    for (int off = 32; off > 0; off >>= 1)
        loss += __shfl_down(loss, off, 64);

    __shared__ float ssum[4];
    int wave = threadIdx.x >> 6;
    int lane = threadIdx.x & 63;
    if (lane == 0) ssum[wave] = loss;
    __syncthreads();
    if (threadIdx.x == 0) {
        float s = ssum[0] + ssum[1] + ssum[2] + ssum[3];
        atomicAdd(out, s * inv_n);
    }
}

extern "C" void kernel_launch(void* const* d_in, const int* in_sizes, int n_in,
                              void* d_out, int out_size, void* d_ws, size_t ws_size,
                              hipStream_t stream) {
    const float* pred   = (const float*)d_in[0];
    const float* target = (const float*)d_in[1];
    const float* weight = (const float*)d_in[2];
    float* out = (float*)d_out;

    int n = in_sizes[0] / 5;

    // d_out is poisoned to 0xAA before every timed launch -> zero it ourselves.
    hipMemsetAsync(out, 0, sizeof(float), stream);

    int block = 256;
    int threads_needed = (n + 3) / 4;
    int grid = (threads_needed + block - 1) / block;
    riou_loss_kernel<<<grid, block, 0, stream>>>(pred, target, weight, out,
                                                 n, 1.0f / (float)n);
}

// Round 6
// 94.164 us; speedup vs baseline: 1.0006x; 1.0006x over previous
//
#include <hip/hip_runtime.h>
#include <math.h>

// RotatedIoULoss: per-pair rotated-box IoU loss, mean-reduced to one f32 scalar.
// Inputs: d_in[0]=pred (n,5) f32, d_in[1]=target (n,5) f32, d_in[2]=weight (n,) f32.
// Output: d_out[0] = mean(-log(max(iou,1e-6)) * weight).
//
// R1: branchless Green's-theorem intersection (generic halfplane Liang-Barsky).
// R2: 4 boxes/thread, float4 loads.
// R3: rectangle-aware AABB slab clipping.
// R4: 4-wide SoA interleave (neutral -> kernel is total-issue bound, not latency).
// R5: cut the issue stream: (a) t1c=max(t1,t0) clamp makes empty intervals
//     contribute exactly-zero cross terms -> zero cmp/cndmask/vcc ops in the
//     clip; (b) shared-slab form t = -s*r -/+ |hw*r| (3 ops/axis, slab consts
//     shared by opposite edges via abs/neg modifiers); (c) fma-everything.
//     ~230 VALU-equiv/box vs ~330, and ~40 mask/SALU ops/box removed.
//     sr==0 guarded to 1e-12 (avoids inf-inf=NaN in shared-slab form).

__device__ __forceinline__ float rcpf(float x) { return __builtin_amdgcn_rcpf(x); }

// Clip edge (start s, dir d, reciprocal r, slab consts au=hw*rx, av=hh*ry —
// signs arbitrary, abs applied here) against AABB [-hw,hw]x[-hh,hh].
// Accumulates Green cross term; TRACK also accumulates net displacement.
// Empty interval => t1c==t0 => start==end => contributions ~0 (no selects).
template <bool TRACK>
__device__ __forceinline__ void clip_edge(float sx, float sy, float dx, float dy,
                                          float rx, float ry, float au, float av,
                                          float& S, float& Dx, float& Dy)
{
    float pu = -sx * rx;
    float pv = -sy * ry;
    float aau = fabsf(au), aav = fabsf(av);
    float tumin = pu - aau, tumax = pu + aau;
    float tvmin = pv - aav, tvmax = pv + aav;
    float t0  = fmaxf(fmaxf(tumin, tvmin), 0.0f);   // v_max3
    float t1  = fminf(fminf(tumax, tvmax), 1.0f);   // v_min3
    float t1c = fmaxf(t1, t0);
    float ax = fmaf(t0,  dx, sx), ay = fmaf(t0,  dy, sy);
    float bx = fmaf(t1c, dx, sx), by = fmaf(t1c, dy, sy);
    S = fmaf(ax, by, S);      // S += cross(a, b)
    S = fmaf(-ay, bx, S);
    if (TRACK) {
        float dt = t1c - t0;
        Dx = fmaf(dt, dx, Dx);
        Dy = fmaf(dt, dy, Dy);
    }
}

// 4-wide SoA quad-vs-AABB clip. Quad k: center (mx,my), half-axis vectors U,V
// (CCW corners +U+V, -U+V, -U-V, +U-V), clip box (hw,hh).
template <bool TRACK>
__device__ __forceinline__ void clip_quad4(const float* Ux, const float* Uy,
                                           const float* Vx, const float* Vy,
                                           const float* mx, const float* my,
                                           const float* hw, const float* hh,
                                           float* S, float* Dx, float* Dy)
{
    float d0x[4], d0y[4], d1x[4], d1y[4];
    float r0x[4], r0y[4], r1x[4], r1y[4];
    float au0[4], av0[4], au1[4], av1[4];
    float c0x[4], c0y[4], c3x[4], c3y[4];
    #pragma unroll
    for (int k = 0; k < 4; k++) {
        d0x[k] = -2.0f * Ux[k]; d0y[k] = -2.0f * Uy[k];   // edge0 dir (+), edge2 (-)
        d1x[k] = -2.0f * Vx[k]; d1y[k] = -2.0f * Vy[k];   // edge1 dir (+), edge3 (-)
        r0x[k] = rcpf(d0x[k]);  r0y[k] = rcpf(d0y[k]);
        r1x[k] = rcpf(d1x[k]);  r1y[k] = rcpf(d1y[k]);
        au0[k] = hw[k] * r0x[k]; av0[k] = hh[k] * r0y[k]; // abs applied at use
        au1[k] = hw[k] * r1x[k]; av1[k] = hh[k] * r1y[k];
        c0x[k] = Ux[k] + Vx[k]; c0y[k] = Uy[k] + Vy[k];   // corner0 offset
        c3x[k] = Ux[k] - Vx[k]; c3y[k] = Uy[k] - Vy[k];   // corner3 offset
    }
    #pragma unroll
    for (int k = 0; k < 4; k++)   // edge0: start m+c0, dir +d0
        clip_edge<TRACK>(mx[k] + c0x[k], my[k] + c0y[k],  d0x[k],  d0y[k],
                          r0x[k],  r0y[k], au0[k], av0[k], S[k], Dx[k], Dy[k]);
    #pragma unroll
    for (int k = 0; k < 4; k++)   // edge1: start m-c3, dir +d1
        clip_edge<TRACK>(mx[k] - c3x[k], my[k] - c3y[k],  d1x[k],  d1y[k],
                          r1x[k],  r1y[k], au1[k], av1[k], S[k], Dx[k], Dy[k]);
    #pragma unroll
    for (int k = 0; k < 4; k++)   // edge2: start m-c0, dir -d0
        clip_edge<TRACK>(mx[k] - c0x[k], my[k] - c0y[k], -d0x[k], -d0y[k],
                         -r0x[k], -r0y[k], au0[k], av0[k], S[k], Dx[k], Dy[k]);
    #pragma unroll
    for (int k = 0; k < 4; k++)   // edge3: start m+c3, dir -d1
        clip_edge<TRACK>(mx[k] + c3x[k], my[k] + c3y[k], -d1x[k], -d1y[k],
                         -r1x[k], -r1y[k], au1[k], av1[k], S[k], Dx[k], Dy[k]);
}

__global__ void __launch_bounds__(256)
riou_loss_kernel(const float* __restrict__ pred,
                 const float* __restrict__ target,
                 const float* __restrict__ weight,
                 float* __restrict__ out,
                 int n, float inv_n)
{
    int t = blockIdx.x * blockDim.x + threadIdx.x;
    int base = t * 4;
    float loss = 0.0f;

    if (base < n) {
        float pp[20], qq[20], ww[4];
        if (base + 4 <= n) {
            // 80 B per thread, 16B-aligned: five float4 loads per input
            const float4* P4 = (const float4*)(pred   + (size_t)base * 5);
            const float4* Q4 = (const float4*)(target + (size_t)base * 5);
            #pragma unroll
            for (int i = 0; i < 5; i++) {
                float4 p = P4[i];
                pp[4 * i + 0] = p.x; pp[4 * i + 1] = p.y;
                pp[4 * i + 2] = p.z; pp[4 * i + 3] = p.w;
                float4 q = Q4[i];
                qq[4 * i + 0] = q.x; qq[4 * i + 1] = q.y;
                qq[4 * i + 2] = q.z; qq[4 * i + 3] = q.w;
            }
            float4 w4 = ((const float4*)weight)[t];
            ww[0] = w4.x; ww[1] = w4.y; ww[2] = w4.z; ww[3] = w4.w;
        } else {
            #pragma unroll
            for (int k = 0; k < 4; k++) {
                int b = base + k; b = (b < n) ? b : (n - 1);
                #pragma unroll
                for (int j = 0; j < 5; j++) {
                    pp[5 * k + j] = pred[(size_t)b * 5 + j];
                    qq[5 * k + j] = target[(size_t)b * 5 + j];
                }
                ww[k] = (base + k < n) ? weight[b] : 0.0f;
            }
        }

        // ---- SoA setup ----
        float hw1[4], hh1[4], hw2[4], hh2[4], a12[4];
        float cr[4], sr[4];
        float cPx[4], cPy[4], cQx[4], cQy[4];
        #pragma unroll
        for (int k = 0; k < 4; k++) {
            float pw = pp[5 * k + 2], ph = pp[5 * k + 3], pa = pp[5 * k + 4];
            float qw = qq[5 * k + 2], qh = qq[5 * k + 3], qa = qq[5 * k + 4];
            hw1[k] = 0.5f * pw; hh1[k] = 0.5f * ph;
            hw2[k] = 0.5f * qw; hh2[k] = 0.5f * qh;
            a12[k] = pw * ph + qw * qh;
            float ca = __cosf(pa), sa = __sinf(pa);
            float delta = pa - qa;
            float c = __cosf(delta), s = __sinf(delta);
            // guard exact-parallel case: shared-slab form would hit inf-inf=NaN
            s = (s == 0.0f) ? 1e-12f : s;
            cr[k] = c; sr[k] = s;
            float ox = qq[5 * k + 0] - pp[5 * k + 0];
            float oy = qq[5 * k + 1] - pp[5 * k + 1];
            // Q center in P-frame: R(-pa) * o
            cPx[k] =  ca * ox + sa * oy;
            cPy[k] = -sa * ox + ca * oy;
            // P center in Q-frame: -R_PQ * cP
            cQx[k] = -(c * cPx[k] - s * cPy[k]);
            cQy[k] = -(s * cPx[k] + c * cPy[k]);
        }

        float S[4]  = {0, 0, 0, 0};
        float Dx[4] = {0, 0, 0, 0};
        float Dy[4] = {0, 0, 0, 0};

        // Set A: P's quad in Q-frame, clipped to (hw2,hh2). U=R_PQ*(hw1,0),
        // V=R_PQ*(0,hh1). Untracked.
        {
            float Ux[4], Uy[4], Vx[4], Vy[4];
            #pragma unroll
            for (int k = 0; k < 4; k++) {
                Ux[k] =  cr[k] * hw1[k]; Uy[k] = sr[k] * hw1[k];
                Vx[k] = -sr[k] * hh1[k]; Vy[k] = cr[k] * hh1[k];
            }
            clip_quad4<false>(Ux, Uy, Vx, Vy, cQx, cQy, hw2, hh2, S, Dx, Dy);
        }
        // Set B: Q's quad in P-frame, clipped to (hw1,hh1). Tracked (for the
        // frame-translation correction).
        {
            float Ux[4], Uy[4], Vx[4], Vy[4];
            #pragma unroll
            for (int k = 0; k < 4; k++) {
                Ux[k] = cr[k] * hw2[k]; Uy[k] = -sr[k] * hw2[k];
                Vx[k] = sr[k] * hh2[k]; Vy[k] =  cr[k] * hh2[k];
            }
            clip_quad4<true>(Ux, Uy, Vx, Vy, cPx, cPy, hw1, hh1, S, Dx, Dy);
        }

        // 2A = S_A + S_B + cross(cQ, R_PQ * D)
        #pragma unroll
        for (int k = 0; k < 4; k++) {
            float RDx = cr[k] * Dx[k] - sr[k] * Dy[k];
            float RDy = sr[k] * Dx[k] + cr[k] * Dy[k];
            float corr = cQx[k] * RDy - cQy[k] * RDx;
            float inter = fmaxf(0.5f * (S[k] + corr), 0.0f);
            float iou = inter * rcpf(a12[k] - inter);
            iou = fmaxf(iou, 1e-6f);
            loss += -__logf(iou) * ww[k];
        }
    }

    // block reduction: wave shuffle (width 64) -> LDS -> one atomic per block
    #pragma unroll
    for (int off = 32; off > 0; off >>= 1)
        loss += __shfl_down(loss, off, 64);

    __shared__ float ssum[4];
    int wave = threadIdx.x >> 6;
    int lane = threadIdx.x & 63;
    if (lane == 0) ssum[wave] = loss;
    __syncthreads();
    if (threadIdx.x == 0) {
        float s = ssum[0] + ssum[1] + ssum[2] + ssum[3];
        atomicAdd(out, s * inv_n);
    }
}

extern "C" void kernel_launch(void* const* d_in, const int* in_sizes, int n_in,
                              void* d_out, int out_size, void* d_ws, size_t ws_size,
                              hipStream_t stream) {
    const float* pred   = (const float*)d_in[0];
    const float* target = (const float*)d_in[1];
    const float* weight = (const float*)d_in[2];
    float* out = (float*)d_out;

    int n = in_sizes[0] / 5;

    // d_out is poisoned to 0xAA before every timed launch -> zero it ourselves.
    hipMemsetAsync(out, 0, sizeof(float), stream);

    int block = 256;
    int threads_needed = (n + 3) / 4;
    int grid = (threads_needed + block - 1) / block;
    riou_loss_kernel<<<grid, block, 0, stream>>>(pred, target, weight, out,
                                                 n, 1.0f / (float)n);
}